// Round 12
// baseline (58.303 us; speedup 1.0000x reference)
//
#include <hip/hip_runtime.h>

typedef short s16x8 __attribute__((ext_vector_type(8)));
typedef float f32x4 __attribute__((ext_vector_type(4)));
typedef unsigned short us4 __attribute__((ext_vector_type(4)));

static __device__ __forceinline__ unsigned short f2bf(float f) {
  unsigned u = __builtin_bit_cast(unsigned, f);
  u += 0x7FFFu + ((u >> 16) & 1u);
  return (unsigned short)(u >> 16);
}

#if __has_builtin(__builtin_amdgcn_exp2f)
#define EXP2(x) __builtin_amdgcn_exp2f(x)
#else
#define EXP2(x) exp2f(x)
#endif

// q pre-scale: (1/sqrt(64)) * log2(e), so P = exp2(score) == e^{qk/8}
#define QSCALE 0.1803368801111204f

#define MFMA16(a, b, c) __builtin_amdgcn_mfma_f32_16x16x32_bf16((a), (b), (c), 0, 0, 0)

// ---------------------------------------------------------------------------
// Projection (r4 structure): out = x @ W^T for q,k,v. Frag-major outputs:
//  q,k: per 16-row chunk c: addr16 = c*1024 + h*512 + lane*8 + e
//       holds Val[row = c*16 + (lane&15)][d = h*32 + (lane>>4)*8 + e]
//       (q pre-scaled by QSCALE = 0.125*log2e for the exp2 softmax)
//  v:   per 64-row chunk c: addr16 = c*4096 + dt*1024 + h*512 + lane*8 + e
//       holds V[s = c*64 + h*32 + (lane>>4)*8 + e][d = dt*16 + (lane&15)]
// ---------------------------------------------------------------------------
__global__ __launch_bounds__(256) void proj_kernel(
    const float* __restrict__ Xq, const float* __restrict__ Xk, const float* __restrict__ Xv,
    const float* __restrict__ Wq, const float* __restrict__ Wk, const float* __restrict__ Wv,
    unsigned short* __restrict__ qf,   // [1024][1024] frag-major
    unsigned short* __restrict__ kf,   // [1024][1024] frag-major
    unsigned short* __restrict__ vfo)  // [256][4096] frag-major
{
  __shared__ __align__(16) unsigned short xs[64][72];
  __shared__ __align__(16) unsigned short ws[64][72];

  const int bid = blockIdx.x;
  const int t = bid >> 8;          // 0=q 1=k 2=v
  const int rb = bid & 255;
  const int b = rb >> 5;
  const int stile = rb & 31;
  const float* X = (t == 0) ? Xq : (t == 1) ? Xk : Xv;
  const float* W = (t == 0) ? Wq : (t == 1) ? Wk : Wv;

  const int tid = threadIdx.x;
  const int wv = tid >> 6;
  const int lane = tid & 63;
  const int j = lane & 15;
  const int g = lane >> 4;

  f32x4 acc[4];
#pragma unroll
  for (int i = 0; i < 4; ++i) acc[i] = {0.f, 0.f, 0.f, 0.f};

  const size_t xrow0 = (size_t)b * 2048 + (size_t)stile * 64;

  for (int kc = 0; kc < 768; kc += 64) {
#pragma unroll
    for (int p = 0; p < 4; ++p) {
      int lin = p * 256 + tid;
      int row = lin >> 4;
      int seg = lin & 15;
      float4 xv = *(const float4*)(X + (xrow0 + row) * 768 + kc + seg * 4);
      us4 px; px.x = f2bf(xv.x); px.y = f2bf(xv.y); px.z = f2bf(xv.z); px.w = f2bf(xv.w);
      *(us4*)&xs[row][seg * 4] = px;
      float4 wv4 = *(const float4*)(W + (size_t)row * 768 + kc + seg * 4);
      us4 pw; pw.x = f2bf(wv4.x); pw.y = f2bf(wv4.y); pw.z = f2bf(wv4.z); pw.w = f2bf(wv4.w);
      *(us4*)&ws[row][seg * 4] = pw;
    }
    __syncthreads();
    s16x8 a0 = *(const s16x8*)&xs[wv * 16 + j][g * 8];
    s16x8 a1 = *(const s16x8*)&xs[wv * 16 + j][32 + g * 8];
#pragma unroll
    for (int ct = 0; ct < 4; ++ct) {
      s16x8 b0 = *(const s16x8*)&ws[ct * 16 + j][g * 8];
      s16x8 b1 = *(const s16x8*)&ws[ct * 16 + j][32 + g * 8];
      acc[ct] = MFMA16(a0, b0, acc[ct]);
      acc[ct] = MFMA16(a1, b1, acc[ct]);
    }
    __syncthreads();
  }

  unsigned short* fb = &xs[0][0];
  if (t < 2) {
    const float sc = (t == 0) ? QSCALE : 1.0f;
#pragma unroll
    for (int ct = 0; ct < 4; ++ct) {
      int base16 = wv * 1024 + ((ct >= 2) ? 512 : 0) + (((ct & 1) * 2 + (j >> 3)) * 128) + (j & 7);
#pragma unroll
      for (int r = 0; r < 4; ++r)
        fb[base16 + (g * 4 + r) * 8] = f2bf(acc[ct][r] * sc);
    }
    __syncthreads();
    unsigned short* dst = ((t == 0) ? qf : kf) + ((size_t)b * 128 + stile * 4) * 1024;
#pragma unroll
    for (int p2 = 0; p2 < 2; ++p2) {
      int idx = p2 * 2048 + tid * 8;
      *(s16x8*)(dst + idx) = *(const s16x8*)&fb[idx];
    }
  } else {
#pragma unroll
    for (int ct = 0; ct < 4; ++ct) {
      us4 pk;
      pk.x = f2bf(acc[ct][0]); pk.y = f2bf(acc[ct][1]);
      pk.z = f2bf(acc[ct][2]); pk.w = f2bf(acc[ct][3]);
      *(us4*)&fb[ct * 1024 + ((wv >= 2) ? 512 : 0) +
                 (((wv & 1) * 2 + (g >> 1)) * 16 + j) * 8 + (g & 1) * 4] = pk;
    }
    __syncthreads();
    unsigned short* gb = vfo + ((size_t)b * 32 + stile) * 4096;
#pragma unroll
    for (int p2 = 0; p2 < 2; ++p2) {
      int idx = p2 * 2048 + tid * 8;
      *(s16x8*)(gb + idx) = *(const s16x8*)&fb[idx];
    }
  }
}

// ---------------------------------------------------------------------------
// Flash attention v9: 64 q-rows per wave (4 row-groups share every K/V
// fragment -> L2 read traffic 128MB). 256 blocks (batch x 64-row tile,
// XCD-pinned) x 4 waves; wave wv sweeps KV chunk [wv*512, wv*512+512) in 8
// kt iterations of 64. QK phase ct-outer/rg-inner (one K-frag pair live at a
// time, exp2+pack immediately). Shift-0 softmax, pure-sum 4-way merge done
// in two 32-row halves so comb unions under p_lds.
// ---------------------------------------------------------------------------
__global__ __launch_bounds__(256, 3) void attn_kernel(
    const unsigned short* __restrict__ qf,  // frag-major (QSCALE-scaled)
    const unsigned short* __restrict__ kf,  // frag-major
    const unsigned short* __restrict__ vf,  // frag-major
    float* __restrict__ out)                // [8][2048][64] f32
{
  __shared__ __align__(16) unsigned char raw[36864];  // p_lds (36864B) / comb (34816B)
  __shared__ float lls[4][32];
  unsigned short* p_lds = (unsigned short*)raw;  // [4 waves][4 rg][16 rows][72]
  float* comb = (float*)raw;                     // [4 chunks][32 rows][68]

  const int tid = threadIdx.x;
  const int wv = tid >> 6;   // wave == kv chunk c (512 positions)
  const int lane = tid & 63;
  const int j = lane & 15;
  const int g = lane >> 4;

  const int bid0 = blockIdx.x;
  const int swz = (bid0 & 7) * 32 + (bid0 >> 3);  // bijective XCD swizzle (256 = 8*32)
  const int b = swz >> 5;
  const int qt = swz & 31;                        // 64-row q tile

  // Q frags for 4 row-groups (rows qt*64 + rg*16 + [0,16))
  s16x8 q0[4], q1[4];
#pragma unroll
  for (int rg = 0; rg < 4; ++rg) {
    const unsigned short* qp =
        qf + ((size_t)(b * 128 + qt * 4 + rg)) * 1024 + lane * 8;
    q0[rg] = *(const s16x8*)(qp);
    q1[rg] = *(const s16x8*)(qp + 512);
  }

  f32x4 o[4][4];
#pragma unroll
  for (int rg = 0; rg < 4; ++rg)
#pragma unroll
    for (int i = 0; i < 4; ++i) o[rg][i] = {0.f, 0.f, 0.f, 0.f};
  float l_acc[4] = {0.f, 0.f, 0.f, 0.f};

  const unsigned short* kfb = kf + (size_t)b * 131072 + wv * 32768 + lane * 8;
  const unsigned short* vfb = vf + (size_t)b * 131072 + wv * 32768 + lane * 8;
  unsigned short* myp[4];
#pragma unroll
  for (int rg = 0; rg < 4; ++rg)
    myp[rg] = p_lds + (size_t)((wv * 4 + rg) * 16 + j) * 72;

  for (int kt = 0; kt < 8; ++kt) {
    const unsigned short* kc_ = kfb + kt * 4096;
    // ---- QK phase: ct-outer, rg-inner; exp2+pack immediately ----
#pragma unroll
    for (int ct = 0; ct < 4; ++ct) {
      s16x8 ka = *(const s16x8*)(kc_ + ct * 1024);
      s16x8 kb2 = *(const s16x8*)(kc_ + ct * 1024 + 512);
#pragma unroll
      for (int rg = 0; rg < 4; ++rg) {
        f32x4 z = {0.f, 0.f, 0.f, 0.f};
        z = MFMA16(ka, q0[rg], z);
        z = MFMA16(kb2, q1[rg], z);
        float p0 = EXP2(z[0]);
        float p1 = EXP2(z[1]);
        float p2 = EXP2(z[2]);
        float p3 = EXP2(z[3]);
        l_acc[rg] += (p0 + p1) + (p2 + p3);
        us4 pk; pk.x = f2bf(p0); pk.y = f2bf(p1); pk.z = f2bf(p2); pk.w = f2bf(p3);
        *(us4*)&myp[rg][ct * 16 + g * 4] = pk;  // P[q=j][k-local]
      }
    }
    // ---- V phase: frags shared by all 4 row-groups ----
    const unsigned short* vc_ = vfb + kt * 4096;
    s16x8 va[4], vb2[4];
#pragma unroll
    for (int dt = 0; dt < 4; ++dt) {
      va[dt] = *(const s16x8*)(vc_ + dt * 1024);
      vb2[dt] = *(const s16x8*)(vc_ + dt * 1024 + 512);
    }
#pragma unroll
    for (int rg = 0; rg < 4; ++rg) {
      s16x8 pa0 = *(const s16x8*)&myp[rg][g * 8];
      s16x8 pa1 = *(const s16x8*)&myp[rg][32 + g * 8];
#pragma unroll
      for (int dt = 0; dt < 4; ++dt) {
        o[rg][dt] = MFMA16(pa0, va[dt], o[rg][dt]);
        o[rg][dt] = MFMA16(pa1, vb2[dt], o[rg][dt]);
      }
    }
  }

  // row-sums of l (lanes j,j+16,j+32,j+48 share q-row j)
#pragma unroll
  for (int rg = 0; rg < 4; ++rg) {
    l_acc[rg] += __shfl_xor(l_acc[rg], 16);
    l_acc[rg] += __shfl_xor(l_acc[rg], 32);
  }

  __syncthreads();  // p_lds dead; raw becomes comb

  // ---- 4-way merge in two 32-row halves (comb = [4][32][68] f32) ----
#pragma unroll
  for (int half = 0; half < 2; ++half) {
#pragma unroll
    for (int rg2 = 0; rg2 < 2; ++rg2) {
      const int rg = half * 2 + rg2;
#pragma unroll
      for (int dt = 0; dt < 4; ++dt)
#pragma unroll
        for (int r = 0; r < 4; ++r)
          comb[((size_t)wv * 32 + rg2 * 16 + g * 4 + r) * 68 + dt * 16 + j] = o[rg][dt][r];
      if (g == 0) lls[wv][rg2 * 16 + j] = l_acc[rg];
    }
    __syncthreads();
#pragma unroll
    for (int it = 0; it < 2; ++it) {
      const int idx = it * 1024 + tid * 4;  // 0..2047, f32x4-aligned
      const int row = idx >> 6;             // 0..31
      const int d0 = idx & 63;
      f32x4 s = {0.f, 0.f, 0.f, 0.f};
      float lt = 0.f;
#pragma unroll
      for (int cc = 0; cc < 4; ++cc) {
        s += *(const f32x4*)&comb[((size_t)cc * 32 + row) * 68 + d0];
        lt += lls[cc][row];
      }
      const float inv = 1.0f / lt;
      f32x4 rr = s * inv;
      *(f32x4*)&out[(((size_t)b * 2048) + qt * 64 + half * 32 + row) * 64 + d0] = rr;
    }
    __syncthreads();  // comb reusable for next half
  }
}

extern "C" void kernel_launch(void* const* d_in, const int* in_sizes, int n_in,
                              void* d_out, int out_size, void* d_ws, size_t ws_size,
                              hipStream_t stream) {
  const float* query = (const float*)d_in[0];
  const float* key_  = (const float*)d_in[1];
  const float* value = (const float*)d_in[2];
  const float* Wq = (const float*)d_in[3];
  const float* Wk = (const float*)d_in[4];
  const float* Wv = (const float*)d_in[5];

  unsigned short* qfb = (unsigned short*)d_ws;      // 1M shorts
  unsigned short* kfb = qfb + 1048576u;             // 1M shorts
  unsigned short* vfb = qfb + 2u * 1048576u;        // 1M shorts
  float* outp = (float*)d_out;

  hipLaunchKernelGGL(proj_kernel, dim3(768), dim3(256), 0, stream,
                     query, key_, value, Wq, Wk, Wv, qfb, kfb, vfb);
  hipLaunchKernelGGL(attn_kernel, dim3(256), dim3(256), 0, stream,
                     qfb, kfb, vfb, outp);
}

// Round 14
// 48.993 us; speedup vs baseline: 1.1900x; 1.1900x over previous
//
#include <hip/hip_runtime.h>
#include <hip/hip_bf16.h>

typedef short s16x8 __attribute__((ext_vector_type(8)));
typedef float f32x4 __attribute__((ext_vector_type(4)));
typedef unsigned short us4 __attribute__((ext_vector_type(4)));

static __device__ __forceinline__ unsigned short f2bf(float f) {
  unsigned u = __builtin_bit_cast(unsigned, f);
  u += 0x7FFFu + ((u >> 16) & 1u);
  return (unsigned short)(u >> 16);
}

// 2x f32 -> packed 2x bf16 via the INTRINSIC (emits v_cvt_pk_bf16_f32;
// compiler-scheduled, unlike r10's inline-asm which regressed).
static __device__ __forceinline__ unsigned pk2(float a, float b) {
  __hip_bfloat162 h = __float22bfloat162_rn(make_float2(a, b));
  unsigned r;
  __builtin_memcpy(&r, &h, 4);  // bit-copy (bfloat162 not trivially copyable)
  return r;                     // a in low 16, b in high 16
}

#if __has_builtin(__builtin_amdgcn_exp2f)
#define EXP2(x) __builtin_amdgcn_exp2f(x)
#else
#define EXP2(x) exp2f(x)
#endif

// q pre-scale: (1/sqrt(64)) * log2(e), so P = exp2(score) == e^{qk/8}
#define QSCALE 0.1803368801111204f

#define MFMA16(a, b, c) __builtin_amdgcn_mfma_f32_16x16x32_bf16((a), (b), (c), 0, 0, 0)

// ---------------------------------------------------------------------------
// Projection (r4 structure): out = x @ W^T for q,k,v. Frag-major outputs:
//  q,k: per 16-row chunk c: addr16 = c*1024 + h*512 + lane*8 + e
//       holds Val[row = c*16 + (lane&15)][d = h*32 + (lane>>4)*8 + e]
//       (q pre-scaled by QSCALE for the exp2 softmax)
//  v:   per 64-row chunk c: addr16 = c*4096 + dt*1024 + h*512 + lane*8 + e
//       holds V[s = c*64 + h*32 + (lane>>4)*8 + e][d = dt*16 + (lane&15)]
// Staging conversion uses v_cvt_pk_bf16_f32 (pk2) -> 4 instrs per float4.
// ---------------------------------------------------------------------------
__global__ __launch_bounds__(256) void proj_kernel(
    const float* __restrict__ Xq, const float* __restrict__ Xk, const float* __restrict__ Xv,
    const float* __restrict__ Wq, const float* __restrict__ Wk, const float* __restrict__ Wv,
    unsigned short* __restrict__ qf,   // [1024][1024] frag-major
    unsigned short* __restrict__ kf,   // [1024][1024] frag-major
    unsigned short* __restrict__ vfo)  // [256][4096] frag-major
{
  __shared__ __align__(16) unsigned short xs[64][72];
  __shared__ __align__(16) unsigned short ws[64][72];

  const int bid = blockIdx.x;
  const int t = bid >> 8;          // 0=q 1=k 2=v
  const int rb = bid & 255;
  const int b = rb >> 5;
  const int stile = rb & 31;
  const float* X = (t == 0) ? Xq : (t == 1) ? Xk : Xv;
  const float* W = (t == 0) ? Wq : (t == 1) ? Wk : Wv;

  const int tid = threadIdx.x;
  const int wv = tid >> 6;
  const int lane = tid & 63;
  const int j = lane & 15;
  const int g = lane >> 4;

  f32x4 acc[4];
#pragma unroll
  for (int i = 0; i < 4; ++i) acc[i] = {0.f, 0.f, 0.f, 0.f};

  const size_t xrow0 = (size_t)b * 2048 + (size_t)stile * 64;

  for (int kc = 0; kc < 768; kc += 64) {
#pragma unroll
    for (int p = 0; p < 4; ++p) {
      int lin = p * 256 + tid;
      int row = lin >> 4;
      int seg = lin & 15;
      float4 xv = *(const float4*)(X + (xrow0 + row) * 768 + kc + seg * 4);
      uint2 ux; ux.x = pk2(xv.x, xv.y); ux.y = pk2(xv.z, xv.w);
      *(uint2*)&xs[row][seg * 4] = ux;
      float4 wv4 = *(const float4*)(W + (size_t)row * 768 + kc + seg * 4);
      uint2 uw; uw.x = pk2(wv4.x, wv4.y); uw.y = pk2(wv4.z, wv4.w);
      *(uint2*)&ws[row][seg * 4] = uw;
    }
    __syncthreads();
    s16x8 a0 = *(const s16x8*)&xs[wv * 16 + j][g * 8];
    s16x8 a1 = *(const s16x8*)&xs[wv * 16 + j][32 + g * 8];
#pragma unroll
    for (int ct = 0; ct < 4; ++ct) {
      s16x8 b0 = *(const s16x8*)&ws[ct * 16 + j][g * 8];
      s16x8 b1 = *(const s16x8*)&ws[ct * 16 + j][32 + g * 8];
      acc[ct] = MFMA16(a0, b0, acc[ct]);
      acc[ct] = MFMA16(a1, b1, acc[ct]);
    }
    __syncthreads();
  }

  unsigned short* fb = &xs[0][0];
  if (t < 2) {
    const float sc = (t == 0) ? QSCALE : 1.0f;
#pragma unroll
    for (int ct = 0; ct < 4; ++ct) {
      int base16 = wv * 1024 + ((ct >= 2) ? 512 : 0) + (((ct & 1) * 2 + (j >> 3)) * 128) + (j & 7);
#pragma unroll
      for (int r = 0; r < 4; ++r)
        fb[base16 + (g * 4 + r) * 8] = f2bf(acc[ct][r] * sc);
    }
    __syncthreads();
    unsigned short* dst = ((t == 0) ? qf : kf) + ((size_t)b * 128 + stile * 4) * 1024;
#pragma unroll
    for (int p2 = 0; p2 < 2; ++p2) {
      int idx = p2 * 2048 + tid * 8;
      *(s16x8*)(dst + idx) = *(const s16x8*)&fb[idx];
    }
  } else {
#pragma unroll
    for (int ct = 0; ct < 4; ++ct) {
      uint2 uv; uv.x = pk2(acc[ct][0], acc[ct][1]); uv.y = pk2(acc[ct][2], acc[ct][3]);
      *(uint2*)&fb[ct * 1024 + ((wv >= 2) ? 512 : 0) +
                   (((wv & 1) * 2 + (g >> 1)) * 16 + j) * 8 + (g & 1) * 4] = uv;
    }
    __syncthreads();
    unsigned short* gb = vfo + ((size_t)b * 32 + stile) * 4096;
#pragma unroll
    for (int p2 = 0; p2 < 2; ++p2) {
      int idx = p2 * 2048 + tid * 8;
      *(s16x8*)(gb + idx) = *(const s16x8*)&fb[idx];
    }
  }
}

// ---------------------------------------------------------------------------
// Flash attention (r9/r11 structure): 32 q-rows/wave (2 row-groups share
// every K/V fragment), 256 blocks (batch x 64-row tile, XCD-pinned) x 8
// waves, shift-0 exp2 softmax, pure-sum merge. Single change vs r11: P
// packing via v_cvt_pk_bf16_f32 intrinsic (8 instrs/kt instead of ~128).
// ---------------------------------------------------------------------------
__global__ __launch_bounds__(512, 4) void attn_kernel(
    const unsigned short* __restrict__ qf,  // frag-major (QSCALE-scaled)
    const unsigned short* __restrict__ kf,  // frag-major
    const unsigned short* __restrict__ vf,  // frag-major
    float* __restrict__ out)                // [8][2048][64] f32
{
  __shared__ __align__(16) unsigned char raw[69632];  // P (36864B) / comb (69632B) union
  __shared__ float lls[8][32];
  unsigned short* p_lds = (unsigned short*)raw;  // [8 waves][2 rg][16 rows][72]
  float* comb = (float*)raw;                     // [8 waves][32 rows][68]

  const int tid = threadIdx.x;
  const int wv = tid >> 6;
  const int lane = tid & 63;
  const int j = lane & 15;
  const int g = lane >> 4;
  const int sg = wv >> 2;   // row supergroup (32 rows)
  const int c = wv & 3;     // kv chunk (512 positions)

  const int bid0 = blockIdx.x;
  const int swz = (bid0 & 7) * 32 + (bid0 >> 3);  // bijective XCD swizzle (256 = 8*32)
  const int b = swz >> 5;
  const int qt = swz & 31;                        // 64-row q tile

  s16x8 q0[2], q1[2];
#pragma unroll
  for (int rg = 0; rg < 2; ++rg) {
    const unsigned short* qp =
        qf + ((size_t)(b * 128 + qt * 4 + sg * 2 + rg)) * 1024 + lane * 8;
    q0[rg] = *(const s16x8*)(qp);
    q1[rg] = *(const s16x8*)(qp + 512);
  }

  f32x4 o[2][4];
#pragma unroll
  for (int rg = 0; rg < 2; ++rg)
#pragma unroll
    for (int i = 0; i < 4; ++i) o[rg][i] = {0.f, 0.f, 0.f, 0.f};
  float l_acc[2] = {0.f, 0.f};

  const unsigned short* kfb = kf + (size_t)b * 131072 + c * 32768 + lane * 8;
  const unsigned short* vfb = vf + (size_t)b * 131072 + c * 32768 + lane * 8;
  unsigned short* myp0 = p_lds + (size_t)((wv * 2 + 0) * 16 + j) * 72;
  unsigned short* myp1 = p_lds + (size_t)((wv * 2 + 1) * 16 + j) * 72;

  for (int kt = 0; kt < 8; ++kt) {
    const unsigned short* kc_ = kfb + kt * 4096;
    s16x8 ka[4], kb2[4];
#pragma unroll
    for (int ct = 0; ct < 4; ++ct) {
      ka[ct] = *(const s16x8*)(kc_ + ct * 1024);
      kb2[ct] = *(const s16x8*)(kc_ + ct * 1024 + 512);
    }
    // ---- rg0: QK^T -> exp2 -> P (cvt_pk pack) ----
    {
      f32x4 st[4];
#pragma unroll
      for (int ct = 0; ct < 4; ++ct) {
        f32x4 z = {0.f, 0.f, 0.f, 0.f};
        z = MFMA16(ka[ct], q0[0], z);
        z = MFMA16(kb2[ct], q1[0], z);
        st[ct] = z;
      }
#pragma unroll
      for (int ct = 0; ct < 4; ++ct) {
        float p0 = EXP2(st[ct][0]);
        float p1 = EXP2(st[ct][1]);
        float p2 = EXP2(st[ct][2]);
        float p3 = EXP2(st[ct][3]);
        l_acc[0] += (p0 + p1) + (p2 + p3);
        uint2 u; u.x = pk2(p0, p1); u.y = pk2(p2, p3);
        *(uint2*)&myp0[ct * 16 + g * 4] = u;
      }
    }
    // ---- rg1: QK^T -> exp2 -> P ----
    {
      f32x4 st[4];
#pragma unroll
      for (int ct = 0; ct < 4; ++ct) {
        f32x4 z = {0.f, 0.f, 0.f, 0.f};
        z = MFMA16(ka[ct], q0[1], z);
        z = MFMA16(kb2[ct], q1[1], z);
        st[ct] = z;
      }
#pragma unroll
      for (int ct = 0; ct < 4; ++ct) {
        float p0 = EXP2(st[ct][0]);
        float p1 = EXP2(st[ct][1]);
        float p2 = EXP2(st[ct][2]);
        float p3 = EXP2(st[ct][3]);
        l_acc[1] += (p0 + p1) + (p2 + p3);
        uint2 u; u.x = pk2(p0, p1); u.y = pk2(p2, p3);
        *(uint2*)&myp1[ct * 16 + g * 4] = u;
      }
    }
    // ---- V frags (shared by both rgs) + PV ----
    const unsigned short* vc_ = vfb + kt * 4096;
    s16x8 va[4], vb2[4];
#pragma unroll
    for (int dt = 0; dt < 4; ++dt) {
      va[dt] = *(const s16x8*)(vc_ + dt * 1024);
      vb2[dt] = *(const s16x8*)(vc_ + dt * 1024 + 512);
    }
    s16x8 pa0 = *(const s16x8*)&myp0[g * 8];
    s16x8 pa1 = *(const s16x8*)&myp0[32 + g * 8];
#pragma unroll
    for (int dt = 0; dt < 4; ++dt) {
      o[0][dt] = MFMA16(pa0, va[dt], o[0][dt]);
      o[0][dt] = MFMA16(pa1, vb2[dt], o[0][dt]);
    }
    s16x8 pb0 = *(const s16x8*)&myp1[g * 8];
    s16x8 pb1 = *(const s16x8*)&myp1[32 + g * 8];
#pragma unroll
    for (int dt = 0; dt < 4; ++dt) {
      o[1][dt] = MFMA16(pb0, va[dt], o[1][dt]);
      o[1][dt] = MFMA16(pb1, vb2[dt], o[1][dt]);
    }
  }

  // row-sums of l (lanes j,j+16,j+32,j+48 share q-row j)
#pragma unroll
  for (int rg = 0; rg < 2; ++rg) {
    l_acc[rg] += __shfl_xor(l_acc[rg], 16);
    l_acc[rg] += __shfl_xor(l_acc[rg], 32);
  }

  __syncthreads();  // all waves done with P; raw becomes comb
#pragma unroll
  for (int rg = 0; rg < 2; ++rg) {
#pragma unroll
    for (int dt = 0; dt < 4; ++dt)
#pragma unroll
      for (int r = 0; r < 4; ++r)
        comb[((size_t)wv * 32 + rg * 16 + g * 4 + r) * 68 + dt * 16 + j] = o[rg][dt][r];
    if (g == 0) lls[wv][rg * 16 + j] = l_acc[rg];
  }
  __syncthreads();

  // merge over the 4 kv chunks (pure sum; shift-0) and normalize
#pragma unroll
  for (int it = 0; it < 8; ++it) {
    const int idx = it * 512 + tid;   // 0..4095
    const int row = idx >> 6;         // 0..63 within block tile
    const int d = idx & 63;
    const int ssg = row >> 5;
    const int srow = row & 31;
    float s = 0.f, lt = 0.f;
#pragma unroll
    for (int cc = 0; cc < 4; ++cc) {
      s += comb[((size_t)(ssg * 4 + cc) * 32 + srow) * 68 + d];
      lt += lls[ssg * 4 + cc][srow];
    }
    out[(((size_t)b * 2048) + qt * 64 + row) * 64 + d] = s / lt;
  }
}

extern "C" void kernel_launch(void* const* d_in, const int* in_sizes, int n_in,
                              void* d_out, int out_size, void* d_ws, size_t ws_size,
                              hipStream_t stream) {
  const float* query = (const float*)d_in[0];
  const float* key_  = (const float*)d_in[1];
  const float* value = (const float*)d_in[2];
  const float* Wq = (const float*)d_in[3];
  const float* Wk = (const float*)d_in[4];
  const float* Wv = (const float*)d_in[5];

  unsigned short* qfb = (unsigned short*)d_ws;      // 1M shorts
  unsigned short* kfb = qfb + 1048576u;             // 1M shorts
  unsigned short* vfb = qfb + 2u * 1048576u;        // 1M shorts
  float* outp = (float*)d_out;

  hipLaunchKernelGGL(proj_kernel, dim3(768), dim3(256), 0, stream,
                     query, key_, value, Wq, Wk, Wv, qfb, kfb, vfb);
  hipLaunchKernelGGL(attn_kernel, dim3(256), dim3(512), 0, stream,
                     qfb, kfb, vfb, outp);
}

// Round 15
// 45.364 us; speedup vs baseline: 1.2852x; 1.0800x over previous
//
#include <hip/hip_runtime.h>
#include <hip/hip_bf16.h>

typedef short s16x8 __attribute__((ext_vector_type(8)));
typedef float f32x4 __attribute__((ext_vector_type(4)));
typedef unsigned short us4 __attribute__((ext_vector_type(4)));

static __device__ __forceinline__ unsigned short f2bf(float f) {
  unsigned u = __builtin_bit_cast(unsigned, f);
  u += 0x7FFFu + ((u >> 16) & 1u);
  return (unsigned short)(u >> 16);
}

// 2x f32 -> packed 2x bf16 via intrinsic (emits v_cvt_pk_bf16_f32)
static __device__ __forceinline__ unsigned pk2(float a, float b) {
  __hip_bfloat162 h = __float22bfloat162_rn(make_float2(a, b));
  unsigned r;
  __builtin_memcpy(&r, &h, 4);
  return r;  // a in low 16, b in high 16
}

#if __has_builtin(__builtin_amdgcn_exp2f)
#define EXP2(x) __builtin_amdgcn_exp2f(x)
#else
#define EXP2(x) exp2f(x)
#endif

// q pre-scale: (1/sqrt(64)) * log2(e), so P = exp2(score) == e^{qk/8}
#define QSCALE 0.1803368801111204f

#define MFMA16(a, b, c) __builtin_amdgcn_mfma_f32_16x16x32_bf16((a), (b), (c), 0, 0, 0)

// ---------------------------------------------------------------------------
// Projection (r4 structure): out = x @ W^T for q,k,v. Frag-major outputs:
//  q,k: per 16-row chunk c: addr16 = c*1024 + h*512 + lane*8 + e
//       holds Val[row = c*16 + (lane&15)][d = h*32 + (lane>>4)*8 + e]
//       (q pre-scaled by QSCALE for the exp2 softmax)
//  v:   per 64-row chunk c: addr16 = c*4096 + dt*1024 + h*512 + lane*8 + e
//       holds V[s = c*64 + h*32 + (lane>>4)*8 + e][d = dt*16 + (lane&15)]
// ---------------------------------------------------------------------------
__global__ __launch_bounds__(256) void proj_kernel(
    const float* __restrict__ Xq, const float* __restrict__ Xk, const float* __restrict__ Xv,
    const float* __restrict__ Wq, const float* __restrict__ Wk, const float* __restrict__ Wv,
    unsigned short* __restrict__ qf,   // [1024][1024] frag-major
    unsigned short* __restrict__ kf,   // [1024][1024] frag-major
    unsigned short* __restrict__ vfo)  // [256][4096] frag-major
{
  __shared__ __align__(16) unsigned short xs[64][72];
  __shared__ __align__(16) unsigned short ws[64][72];

  const int bid = blockIdx.x;
  const int t = bid >> 8;          // 0=q 1=k 2=v
  const int rb = bid & 255;
  const int b = rb >> 5;
  const int stile = rb & 31;
  const float* X = (t == 0) ? Xq : (t == 1) ? Xk : Xv;
  const float* W = (t == 0) ? Wq : (t == 1) ? Wk : Wv;

  const int tid = threadIdx.x;
  const int wv = tid >> 6;
  const int lane = tid & 63;
  const int j = lane & 15;
  const int g = lane >> 4;

  f32x4 acc[4];
#pragma unroll
  for (int i = 0; i < 4; ++i) acc[i] = {0.f, 0.f, 0.f, 0.f};

  const size_t xrow0 = (size_t)b * 2048 + (size_t)stile * 64;

  for (int kc = 0; kc < 768; kc += 64) {
#pragma unroll
    for (int p = 0; p < 4; ++p) {
      int lin = p * 256 + tid;
      int row = lin >> 4;
      int seg = lin & 15;
      float4 xv = *(const float4*)(X + (xrow0 + row) * 768 + kc + seg * 4);
      uint2 ux; ux.x = pk2(xv.x, xv.y); ux.y = pk2(xv.z, xv.w);
      *(uint2*)&xs[row][seg * 4] = ux;
      float4 wv4 = *(const float4*)(W + (size_t)row * 768 + kc + seg * 4);
      uint2 uw; uw.x = pk2(wv4.x, wv4.y); uw.y = pk2(wv4.z, wv4.w);
      *(uint2*)&ws[row][seg * 4] = uw;
    }
    __syncthreads();
    s16x8 a0 = *(const s16x8*)&xs[wv * 16 + j][g * 8];
    s16x8 a1 = *(const s16x8*)&xs[wv * 16 + j][32 + g * 8];
#pragma unroll
    for (int ct = 0; ct < 4; ++ct) {
      s16x8 b0 = *(const s16x8*)&ws[ct * 16 + j][g * 8];
      s16x8 b1 = *(const s16x8*)&ws[ct * 16 + j][32 + g * 8];
      acc[ct] = MFMA16(a0, b0, acc[ct]);
      acc[ct] = MFMA16(a1, b1, acc[ct]);
    }
    __syncthreads();
  }

  unsigned short* fb = &xs[0][0];
  if (t < 2) {
    const float sc = (t == 0) ? QSCALE : 1.0f;
#pragma unroll
    for (int ct = 0; ct < 4; ++ct) {
      int base16 = wv * 1024 + ((ct >= 2) ? 512 : 0) + (((ct & 1) * 2 + (j >> 3)) * 128) + (j & 7);
#pragma unroll
      for (int r = 0; r < 4; ++r)
        fb[base16 + (g * 4 + r) * 8] = f2bf(acc[ct][r] * sc);
    }
    __syncthreads();
    unsigned short* dst = ((t == 0) ? qf : kf) + ((size_t)b * 128 + stile * 4) * 1024;
#pragma unroll
    for (int p2 = 0; p2 < 2; ++p2) {
      int idx = p2 * 2048 + tid * 8;
      *(s16x8*)(dst + idx) = *(const s16x8*)&fb[idx];
    }
  } else {
#pragma unroll
    for (int ct = 0; ct < 4; ++ct) {
      uint2 uv; uv.x = pk2(acc[ct][0], acc[ct][1]); uv.y = pk2(acc[ct][2], acc[ct][3]);
      *(uint2*)&fb[ct * 1024 + ((wv >= 2) ? 512 : 0) +
                   (((wv & 1) * 2 + (g >> 1)) * 16 + j) * 8 + (g & 1) * 4] = uv;
    }
    __syncthreads();
    unsigned short* gb = vfo + ((size_t)b * 32 + stile) * 4096;
#pragma unroll
    for (int p2 = 0; p2 < 2; ++p2) {
      int idx = p2 * 2048 + tid * 8;
      *(s16x8*)(gb + idx) = *(const s16x8*)&fb[idx];
    }
  }
}

// ---------------------------------------------------------------------------
// Flash attention v10: r9 wave shape (32 q-rows, 2-rg K/V reuse) at DOUBLE
// occupancy via 8-way split-K. 512 blocks (batch x 32-row q-tile, XCD
// swizzle 8x64) x 8 waves (512 thr); all waves share the block's 32 rows,
// wave wv owns KV chunk [wv*256, wv*256+256) = 4 kt of 64. 4096 waves =
// 4 waves/SIMD, 2 blocks/CU. Shift-0 exp2 softmax; pure-sum merge over the
// 8 chunks (comb unions under p_lds).
// ---------------------------------------------------------------------------
__global__ __launch_bounds__(512, 4) void attn_kernel(
    const unsigned short* __restrict__ qf,  // frag-major (QSCALE-scaled)
    const unsigned short* __restrict__ kf,  // frag-major
    const unsigned short* __restrict__ vf,  // frag-major
    float* __restrict__ out)                // [8][2048][64] f32
{
  __shared__ __align__(16) unsigned char raw[69632];  // P (36864B) / comb (69632B) union
  __shared__ float lls[8][32];
  unsigned short* p_lds = (unsigned short*)raw;  // [8 waves][2 rg][16 rows][72]
  float* comb = (float*)raw;                     // [8 chunks][32 rows][68]

  const int tid = threadIdx.x;
  const int wv = tid >> 6;   // wave == kv chunk (256 positions)
  const int lane = tid & 63;
  const int j = lane & 15;
  const int g = lane >> 4;

  const int bid0 = blockIdx.x;
  const int swz = (bid0 & 7) * 64 + (bid0 >> 3);  // bijective XCD swizzle (512 = 8*64)
  const int b = swz >> 6;
  const int qt = swz & 63;                        // 32-row q tile

  // Q frags for the block's two 16-row groups (rows qt*32 + rg*16 + [0,16))
  s16x8 q0[2], q1[2];
#pragma unroll
  for (int rg = 0; rg < 2; ++rg) {
    const unsigned short* qp =
        qf + ((size_t)(b * 128 + qt * 2 + rg)) * 1024 + lane * 8;
    q0[rg] = *(const s16x8*)(qp);
    q1[rg] = *(const s16x8*)(qp + 512);
  }

  f32x4 o[2][4];
#pragma unroll
  for (int rg = 0; rg < 2; ++rg)
#pragma unroll
    for (int i = 0; i < 4; ++i) o[rg][i] = {0.f, 0.f, 0.f, 0.f};
  float l_acc[2] = {0.f, 0.f};

  const unsigned short* kfb = kf + (size_t)b * 131072 + wv * 16384 + lane * 8;
  const unsigned short* vfb = vf + (size_t)b * 131072 + wv * 16384 + lane * 8;
  unsigned short* myp0 = p_lds + (size_t)((wv * 2 + 0) * 16 + j) * 72;
  unsigned short* myp1 = p_lds + (size_t)((wv * 2 + 1) * 16 + j) * 72;

  for (int kt = 0; kt < 4; ++kt) {
    const unsigned short* kc_ = kfb + kt * 4096;
    s16x8 ka[4], kb2[4];
#pragma unroll
    for (int ct = 0; ct < 4; ++ct) {
      ka[ct] = *(const s16x8*)(kc_ + ct * 1024);
      kb2[ct] = *(const s16x8*)(kc_ + ct * 1024 + 512);
    }
    // ---- rg0: QK^T -> exp2 -> P ----
    {
      f32x4 st[4];
#pragma unroll
      for (int ct = 0; ct < 4; ++ct) {
        f32x4 z = {0.f, 0.f, 0.f, 0.f};
        z = MFMA16(ka[ct], q0[0], z);
        z = MFMA16(kb2[ct], q1[0], z);
        st[ct] = z;
      }
#pragma unroll
      for (int ct = 0; ct < 4; ++ct) {
        float p0 = EXP2(st[ct][0]);
        float p1 = EXP2(st[ct][1]);
        float p2 = EXP2(st[ct][2]);
        float p3 = EXP2(st[ct][3]);
        l_acc[0] += (p0 + p1) + (p2 + p3);
        uint2 u; u.x = pk2(p0, p1); u.y = pk2(p2, p3);
        *(uint2*)&myp0[ct * 16 + g * 4] = u;
      }
    }
    // ---- rg1: QK^T -> exp2 -> P ----
    {
      f32x4 st[4];
#pragma unroll
      for (int ct = 0; ct < 4; ++ct) {
        f32x4 z = {0.f, 0.f, 0.f, 0.f};
        z = MFMA16(ka[ct], q0[1], z);
        z = MFMA16(kb2[ct], q1[1], z);
        st[ct] = z;
      }
#pragma unroll
      for (int ct = 0; ct < 4; ++ct) {
        float p0 = EXP2(st[ct][0]);
        float p1 = EXP2(st[ct][1]);
        float p2 = EXP2(st[ct][2]);
        float p3 = EXP2(st[ct][3]);
        l_acc[1] += (p0 + p1) + (p2 + p3);
        uint2 u; u.x = pk2(p0, p1); u.y = pk2(p2, p3);
        *(uint2*)&myp1[ct * 16 + g * 4] = u;
      }
    }
    // ---- V frags (shared by both rgs) + PV ----
    const unsigned short* vc_ = vfb + kt * 4096;
    s16x8 va[4], vb2[4];
#pragma unroll
    for (int dt = 0; dt < 4; ++dt) {
      va[dt] = *(const s16x8*)(vc_ + dt * 1024);
      vb2[dt] = *(const s16x8*)(vc_ + dt * 1024 + 512);
    }
    s16x8 pa0 = *(const s16x8*)&myp0[g * 8];
    s16x8 pa1 = *(const s16x8*)&myp0[32 + g * 8];
#pragma unroll
    for (int dt = 0; dt < 4; ++dt) {
      o[0][dt] = MFMA16(pa0, va[dt], o[0][dt]);
      o[0][dt] = MFMA16(pa1, vb2[dt], o[0][dt]);
    }
    s16x8 pb0 = *(const s16x8*)&myp1[g * 8];
    s16x8 pb1 = *(const s16x8*)&myp1[32 + g * 8];
#pragma unroll
    for (int dt = 0; dt < 4; ++dt) {
      o[1][dt] = MFMA16(pb0, va[dt], o[1][dt]);
      o[1][dt] = MFMA16(pb1, vb2[dt], o[1][dt]);
    }
  }

  // row-sums of l (lanes j,j+16,j+32,j+48 share q-row j)
#pragma unroll
  for (int rg = 0; rg < 2; ++rg) {
    l_acc[rg] += __shfl_xor(l_acc[rg], 16);
    l_acc[rg] += __shfl_xor(l_acc[rg], 32);
  }

  __syncthreads();  // all waves done with P; raw becomes comb
#pragma unroll
  for (int rg = 0; rg < 2; ++rg) {
#pragma unroll
    for (int dt = 0; dt < 4; ++dt)
#pragma unroll
      for (int r = 0; r < 4; ++r)
        comb[((size_t)wv * 32 + rg * 16 + g * 4 + r) * 68 + dt * 16 + j] = o[rg][dt][r];
    if (g == 0) lls[wv][rg * 16 + j] = l_acc[rg];
  }
  __syncthreads();

  // merge over the 8 kv chunks (pure sum; shift-0) and normalize
#pragma unroll
  for (int it = 0; it < 4; ++it) {
    const int idx = it * 512 + tid;   // 0..2047
    const int row = idx >> 6;         // 0..31 within block tile
    const int d = idx & 63;
    float s = 0.f, lt = 0.f;
#pragma unroll
    for (int cc = 0; cc < 8; ++cc) {
      s += comb[((size_t)cc * 32 + row) * 68 + d];
      lt += lls[cc][row];
    }
    out[(((size_t)b * 2048) + qt * 32 + row) * 64 + d] = s / lt;
  }
}

extern "C" void kernel_launch(void* const* d_in, const int* in_sizes, int n_in,
                              void* d_out, int out_size, void* d_ws, size_t ws_size,
                              hipStream_t stream) {
  const float* query = (const float*)d_in[0];
  const float* key_  = (const float*)d_in[1];
  const float* value = (const float*)d_in[2];
  const float* Wq = (const float*)d_in[3];
  const float* Wk = (const float*)d_in[4];
  const float* Wv = (const float*)d_in[5];

  unsigned short* qfb = (unsigned short*)d_ws;      // 1M shorts
  unsigned short* kfb = qfb + 1048576u;             // 1M shorts
  unsigned short* vfb = qfb + 2u * 1048576u;        // 1M shorts
  float* outp = (float*)d_out;

  hipLaunchKernelGGL(proj_kernel, dim3(768), dim3(256), 0, stream,
                     query, key_, value, Wq, Wk, Wv, qfb, kfb, vfb);
  hipLaunchKernelGGL(attn_kernel, dim3(512), dim3(512), 0, stream,
                     qfb, kfb, vfb, outp);
}